// Round 2
// baseline (3061.804 us; speedup 1.0000x reference)
//
#include <hip/hip_runtime.h>
#include <hip/hip_bf16.h>

#define N_NODES 10000
#define SEQ_T 12
#define IN_CH 16
#define HID 64
#define N_EDGES 160000

// ---- helpers ----
__device__ __forceinline__ float sigmf(float x){ return 1.0f / (1.0f + __expf(-x)); }
__device__ __forceinline__ float tanh_fast(float x){ return 1.0f - 2.0f / (1.0f + __expf(2.0f * x)); }

// wb (fp32 workspace param block) layout, in floats:
//   0     wT_ih0 [k*192+r]   12288
//   12288 wT_hh0             12288
//   24576 wT_ih1             12288
//   36864 wT_hh1             12288
//   49152 b_ih0 192 | 49344 b_hh0 192 | 49536 b_ih1 192 | 49728 b_hh1 192
//   49920 gcn_w 1024 | 50944 gcn_b 64
//   51008 attn_w 64 | 51072 attn_b 1 | 51073 fc_w 64 | 51137 fc_b 1

// ---- param transpose/copy (fp32 inputs) + deg init ----
__global__ void k_prep(const float* __restrict__ gcn_w,
                       const float* __restrict__ gcn_b,
                       const float* __restrict__ wih0,
                       const float* __restrict__ whh0,
                       const float* __restrict__ bih0,
                       const float* __restrict__ bhh0,
                       const float* __restrict__ wih1,
                       const float* __restrict__ whh1,
                       const float* __restrict__ bih1,
                       const float* __restrict__ bhh1,
                       const float* __restrict__ attn_w,
                       const float* __restrict__ attn_b,
                       const float* __restrict__ fc_w,
                       const float* __restrict__ fc_b,
                       float* __restrict__ wb, float* __restrict__ deg){
  int p = blockIdx.y;
  int i = blockIdx.x * 256 + threadIdx.x;
  if (p == 14){ if (i < N_NODES) deg[i] = 1.0f; return; }
  const float* srcs[14] = {wih0, whh0, wih1, whh1, bih0, bhh0, bih1, bhh1,
                           gcn_w, gcn_b, attn_w, attn_b, fc_w, fc_b};
  const int sizes[14] = {12288,12288,12288,12288,192,192,192,192,1024,64,64,1,64,1};
  const int dsts[14]  = {0,12288,24576,36864,49152,49344,49536,49728,49920,50944,51008,51072,51073,51137};
  if (i >= sizes[p]) return;
  float v = srcs[p][i];
  int o = dsts[p];
  if (p < 4){ int r = i >> 6, k = i & 63; wb[o + k * 192 + r] = v; }  // wT[k][r]
  else wb[o + i] = v;
}

// ---- degree count (in-degree over dst; deg pre-initialized to 1 for self loop) ----
__global__ void k_deg(const int* __restrict__ ei, float* __restrict__ deg){
  int e = blockIdx.x * 256 + threadIdx.x;
  if (e < N_EDGES) atomicAdd(&deg[ei[N_EDGES + e]], 1.0f);
}

__global__ void k_dis(const float* __restrict__ deg, float* __restrict__ dis){
  int n = blockIdx.x * 256 + threadIdx.x;
  if (n < N_NODES) dis[n] = rsqrtf(deg[n]);
}

// ---- GCN neighbor scatter: agg[t][dst][f] += dis[s]*dis[d]*x[t][src][f] ----
__global__ void k_scatter(const float* __restrict__ x, const int* __restrict__ ei,
                          const float* __restrict__ dis, float* __restrict__ agg){
  int e = blockIdx.x * 256 + threadIdx.x;
  if (e >= N_EDGES) return;
  int t = blockIdx.y;
  int s = ei[e], d = ei[N_EDGES + e];
  float nm = dis[s] * dis[d];
  const float* xp = x + ((size_t)t * N_NODES + s) * IN_CH;
  float* ap = agg + ((size_t)t * N_NODES + d) * IN_CH;
  float4 v0 = *(const float4*)(xp);
  float4 v1 = *(const float4*)(xp + 4);
  float4 v2 = *(const float4*)(xp + 8);
  float4 v3 = *(const float4*)(xp + 12);
  float vv[16] = {v0.x,v0.y,v0.z,v0.w, v1.x,v1.y,v1.z,v1.w,
                  v2.x,v2.y,v2.z,v2.w, v3.x,v3.y,v3.z,v3.w};
  #pragma unroll
  for (int q = 0; q < 16; ++q) atomicAdd(ap + q, nm * vv[q]);
}

// ---- GCN matmul + self loop + relu -> gcn_out[t][h][n] ----
__global__ void k_gcn(const float* __restrict__ agg, const float* __restrict__ x,
                      const float* __restrict__ dis, const float* __restrict__ wb,
                      float* __restrict__ out){
  int t = blockIdx.z;
  int lane = threadIdx.x & 63;
  int h = blockIdx.y * 4 + (threadIdx.x >> 6);   // wave-uniform h
  int n = blockIdx.x * 64 + lane;
  bool valid = n < N_NODES;
  int nc = valid ? n : 0;
  const float* gw = wb + 49920;
  float d2 = dis[nc]; d2 = d2 * d2;              // 1/deg (self-loop norm)
  float sacc = wb[50944 + h];
  size_t base = ((size_t)t * N_NODES + nc) * IN_CH;
  #pragma unroll
  for (int f = 0; f < IN_CH; ++f){
    float v = agg[base + f] + d2 * x[base + f];
    sacc = fmaf(v, gw[f * HID + h], sacc);
  }
  if (valid) out[((size_t)t * HID + h) * N_NODES + n] = fmaxf(sacc, 0.0f);
}

// ---- fused 2-layer GRU. block = 64 nodes (lane=node), 8 waves x 8 gate-triples ----
__global__ __launch_bounds__(512) void k_gru(const float* __restrict__ x,
                                             const float* __restrict__ wb,
                                             float* __restrict__ out){
  __shared__ float h0[HID][65];   // [hidden k][node n], pad 65 -> conflict-free
  __shared__ float h1[HID][65];
  const int lane = threadIdx.x & 63;
  const int j0 = (threadIdx.x >> 6) * 8;       // wave-uniform gate-triple base
  const int gn = blockIdx.x * 64 + lane;
  const bool valid = gn < N_NODES;
  for (int i = threadIdx.x; i < HID * 65; i += 512){
    (&h0[0][0])[i] = 0.0f; (&h1[0][0])[i] = 0.0f;
  }
  __syncthreads();
  const float* wih[2] = {wb,         wb + 24576};
  const float* whh[2] = {wb + 12288, wb + 36864};
  const float* bih[2] = {wb + 49152, wb + 49536};
  const float* bhh[2] = {wb + 49344, wb + 49728};
  for (int t = 0; t < SEQ_T; ++t){
    #pragma unroll
    for (int layer = 0; layer < 2; ++layer){
      float ax[3][8], ah[3][8];
      #pragma unroll
      for (int g = 0; g < 3; ++g)
        #pragma unroll
        for (int jj = 0; jj < 8; ++jj){
          ax[g][jj] = bih[layer][g * 64 + j0 + jj];
          ah[g][jj] = bhh[layer][g * 64 + j0 + jj];
        }
      const float* xt = x + (size_t)t * HID * N_NODES + gn;
      float (*hin)[65] = (layer == 0) ? h0 : h1;
      #pragma unroll 2
      for (int k = 0; k < HID; ++k){
        // input: layer0 from gcn_out (global, coalesced over nodes); layer1 from h0 (LDS)
        float xk = (layer == 0) ? (valid ? xt[(size_t)k * N_NODES] : 0.0f) : h0[k][lane];
        float hk = hin[k][lane];
        const float* wi = wih[layer] + k * 192 + j0;   // wave-uniform -> s_load
        const float* wh = whh[layer] + k * 192 + j0;
        #pragma unroll
        for (int g = 0; g < 3; ++g)
          #pragma unroll
          for (int jj = 0; jj < 8; ++jj){
            ax[g][jj] = fmaf(wi[g * 64 + jj], xk, ax[g][jj]);
            ah[g][jj] = fmaf(wh[g * 64 + jj], hk, ah[g][jj]);
          }
      }
      float hnew[8];
      #pragma unroll
      for (int jj = 0; jj < 8; ++jj){
        float hprev = hin[j0 + jj][lane];
        float r  = sigmf(ax[0][jj] + ah[0][jj]);
        float z  = sigmf(ax[1][jj] + ah[1][jj]);
        float ng = tanh_fast(ax[2][jj] + r * ah[2][jj]);
        hnew[jj] = (1.0f - z) * ng + z * hprev;
      }
      __syncthreads();              // all waves done reading old h
      #pragma unroll
      for (int jj = 0; jj < 8; ++jj) hin[j0 + jj][lane] = hnew[jj];
      if (layer == 1 && valid){
        #pragma unroll
        for (int jj = 0; jj < 8; ++jj)
          out[((size_t)t * HID + j0 + jj) * N_NODES + gn] = hnew[jj];
      }
      __syncthreads();              // h updated before next consumer
    }
  }
}

// ---- attention + fc + residual ----
__global__ void k_attn(const float* __restrict__ gru, const float* __restrict__ x,
                       const float* __restrict__ wb, float* __restrict__ out){
  int n = blockIdx.x * 64 + threadIdx.x;
  if (n >= N_NODES) return;
  const float* aw = wb + 51008;
  float ab = wb[51072];
  const float* fw = wb + 51073;
  float fb = wb[51137];
  float sc[SEQ_T], dc[SEQ_T];
  #pragma unroll
  for (int t = 0; t < SEQ_T; ++t){
    float s = ab, d = 0.0f;
    #pragma unroll
    for (int k = 0; k < HID; ++k){
      float v = gru[((size_t)t * HID + k) * N_NODES + n];
      s = fmaf(v, aw[k], s);
      d = fmaf(v, fw[k], d);
    }
    sc[t] = s; dc[t] = d;
  }
  float m = sc[0];
  #pragma unroll
  for (int t = 1; t < SEQ_T; ++t) m = fmaxf(m, sc[t]);
  float den = 0.0f, num = 0.0f;
  #pragma unroll
  for (int t = 0; t < SEQ_T; ++t){
    float p = __expf(sc[t] - m);
    den += p;
    num = fmaf(p, dc[t], num);
  }
  float y = fb + num / den;
  float last = x[((size_t)(SEQ_T - 1) * N_NODES + n) * IN_CH];   // x[11][n][0]
  out[n] = last + y;
}

extern "C" void kernel_launch(void* const* d_in, const int* in_sizes, int n_in,
                              void* d_out, int out_size, void* d_ws, size_t ws_size,
                              hipStream_t stream){
  const float* x = (const float*)d_in[0];   // fp32, (T,N,16)
  const int* ei  = (const int*)d_in[1];     // (2,E)
  char* ws = (char*)d_ws;
  float* wb   = (float*)(ws);                 // 51138 floats (<256KB)
  float* deg  = (float*)(ws + 262144);        // N floats
  float* dis  = (float*)(ws + 303104);        // N floats
  float* agg  = (float*)(ws + 344064);        // T*N*16 fp32 = 7,680,000 B
  float* gout = (float*)(ws + 8024064);       // (T,64,N) fp32 = 30,720,000 B
  float* ghid = (float*)(ws + 38744064);      // (T,64,N) fp32 = 30,720,000 B

  hipMemsetAsync(agg, 0, (size_t)SEQ_T * N_NODES * IN_CH * sizeof(float), stream);

  k_prep<<<dim3(48, 15), 256, 0, stream>>>(
      (const float*)d_in[2],  (const float*)d_in[3],
      (const float*)d_in[4],  (const float*)d_in[5],
      (const float*)d_in[6],  (const float*)d_in[7],
      (const float*)d_in[8],  (const float*)d_in[9],
      (const float*)d_in[10], (const float*)d_in[11],
      (const float*)d_in[12], (const float*)d_in[13],
      (const float*)d_in[14], (const float*)d_in[15],
      wb, deg);
  k_deg<<<(N_EDGES + 255) / 256, 256, 0, stream>>>(ei, deg);
  k_dis<<<(N_NODES + 255) / 256, 256, 0, stream>>>(deg, dis);
  k_scatter<<<dim3(N_EDGES / 256, SEQ_T), 256, 0, stream>>>(x, ei, dis, agg);
  k_gcn<<<dim3((N_NODES + 63) / 64, 16, SEQ_T), 256, 0, stream>>>(agg, x, dis, wb, gout);
  k_gru<<<(N_NODES + 63) / 64, 512, 0, stream>>>(gout, wb, ghid);
  k_attn<<<(N_NODES + 63) / 64, 64, 0, stream>>>(ghid, x, wb, (float*)d_out);
}

// Round 3
// 1466.548 us; speedup vs baseline: 2.0878x; 2.0878x over previous
//
#include <hip/hip_runtime.h>
#include <hip/hip_bf16.h>

#define N_NODES 10000
#define SEQ_T 12
#define IN_CH 16
#define HID 64
#define N_EDGES 160000

// ---- helpers ----
__device__ __forceinline__ float sigmf(float x){ return 1.0f / (1.0f + __expf(-x)); }
__device__ __forceinline__ float tanh_fast(float x){ return 1.0f - 2.0f / (1.0f + __expf(2.0f * x)); }

// wb (fp32 workspace param block) layout, in floats:
//   0     wT_ih0 [k*192+r]   12288
//   12288 wT_hh0             12288
//   24576 wT_ih1             12288
//   36864 wT_hh1             12288
//   49152 b_ih0 192 | 49344 b_hh0 192 | 49536 b_ih1 192 | 49728 b_hh1 192
//   49920 gcn_w 1024 | 50944 gcn_b 64
//   51008 attn_w 64 | 51072 attn_b 1 | 51073 fc_w 64 | 51137 fc_b 1

// ---- param transpose/copy (fp32 inputs) + cnt zero-init ----
__global__ void k_prep(const float* __restrict__ gcn_w,
                       const float* __restrict__ gcn_b,
                       const float* __restrict__ wih0,
                       const float* __restrict__ whh0,
                       const float* __restrict__ bih0,
                       const float* __restrict__ bhh0,
                       const float* __restrict__ wih1,
                       const float* __restrict__ whh1,
                       const float* __restrict__ bih1,
                       const float* __restrict__ bhh1,
                       const float* __restrict__ attn_w,
                       const float* __restrict__ attn_b,
                       const float* __restrict__ fc_w,
                       const float* __restrict__ fc_b,
                       float* __restrict__ wb, int* __restrict__ cnt){
  int p = blockIdx.y;
  int i = blockIdx.x * 256 + threadIdx.x;
  if (p == 14){ if (i < N_NODES) cnt[i] = 0; return; }
  const float* srcs[14] = {wih0, whh0, wih1, whh1, bih0, bhh0, bih1, bhh1,
                           gcn_w, gcn_b, attn_w, attn_b, fc_w, fc_b};
  const int sizes[14] = {12288,12288,12288,12288,192,192,192,192,1024,64,64,1,64,1};
  const int dsts[14]  = {0,12288,24576,36864,49152,49344,49536,49728,49920,50944,51008,51072,51073,51137};
  if (i >= sizes[p]) return;
  float v = srcs[p][i];
  int o = dsts[p];
  if (p < 4){ int r = i >> 6, k = i & 63; wb[o + k * 192 + r] = v; }  // wT[k][r]
  else wb[o + i] = v;
}

// ---- in-degree count over dst (int atomics, 160k total) ----
__global__ void k_count(const int* __restrict__ ei, int* __restrict__ cnt){
  int e = blockIdx.x * 256 + threadIdx.x;
  if (e < N_EDGES) atomicAdd(&cnt[ei[N_EDGES + e]], 1);
}

// ---- exclusive scan of cnt -> row offsets; also dis = rsqrt(cnt+1); cursor=row (aliases cnt) ----
__global__ __launch_bounds__(1024) void k_scan(int* __restrict__ cnt_cursor,
                                               int* __restrict__ row,
                                               float* __restrict__ dis){
  __shared__ int sums[1024];
  const int CH = 10;                       // 1024*10 >= 10000
  int tid = threadIdx.x;
  int base = tid * CH;
  int local[CH]; int s = 0;
  #pragma unroll
  for (int i = 0; i < CH; ++i){
    int idx = base + i;
    int v = (idx < N_NODES) ? cnt_cursor[idx] : 0;
    local[i] = s;                          // thread-local exclusive prefix
    s += v;
    if (idx < N_NODES) dis[idx] = rsqrtf((float)v + 1.0f);  // deg = in-count + self loop
  }
  sums[tid] = s;
  __syncthreads();
  for (int off = 1; off < 1024; off <<= 1){
    int v = (tid >= off) ? sums[tid - off] : 0;
    __syncthreads();
    sums[tid] += v;
    __syncthreads();
  }
  int excl = sums[tid] - s;
  #pragma unroll
  for (int i = 0; i < CH; ++i){
    int idx = base + i;
    if (idx < N_NODES){
      int r = excl + local[i];
      row[idx] = r;
      cnt_cursor[idx] = r;                 // becomes the fill cursor (safe: own reads done)
    }
  }
  if (tid == 1023) row[N_NODES] = sums[1023];
}

// ---- CSR fill: place each edge at its dst slot, store src + norm weight ----
__global__ void k_fill(const int* __restrict__ ei, int* __restrict__ cursor,
                       const float* __restrict__ dis,
                       int* __restrict__ csr_src, float* __restrict__ csr_w){
  int e = blockIdx.x * 256 + threadIdx.x;
  if (e >= N_EDGES) return;
  int s = ei[e], d = ei[N_EDGES + e];
  int pos = atomicAdd(&cursor[d], 1);
  csr_src[pos] = s;
  csr_w[pos] = dis[s] * dis[d];
}

// ---- fused gather + GCN matmul + bias + relu -> gout[t][h][n] ----
// 16 lanes = 16 input channels of one (t,dst) group; 16 groups per block.
__global__ __launch_bounds__(256) void k_gather_gcn(
    const float* __restrict__ x, const int* __restrict__ row,
    const int* __restrict__ csr_src, const float* __restrict__ csr_w,
    const float* __restrict__ dis, const float* __restrict__ wb,
    float* __restrict__ gout){
  __shared__ float sm[16][16];             // stride 16: 2-way bank alias only (free)
  __shared__ float smw[IN_CH * HID];
  __shared__ float smb[HID];
  int tid = threadIdx.x;
  for (int i = tid; i < IN_CH * HID; i += 256) smw[i] = wb[49920 + i];
  if (tid < HID) smb[tid] = wb[50944 + tid];
  int grp = tid >> 4, ch = tid & 15;
  int gid = blockIdx.x * 16 + grp;         // 7500*16 == 120000 exact
  int t = gid / N_NODES, dst = gid - t * N_NODES;
  float dd = dis[dst];
  float acc = dd * dd * x[((size_t)t * N_NODES + dst) * IN_CH + ch];   // self loop
  int r0 = row[dst], r1 = row[dst + 1];
  for (int e = r0; e < r1; ++e){
    int s = csr_src[e];                    // broadcast within group
    float w = csr_w[e];
    acc = fmaf(w, x[((size_t)t * N_NODES + s) * IN_CH + ch], acc);
  }
  sm[grp][ch] = acc;
  __syncthreads();                          // covers smw/smb fill + sm writes
  float v[16];
  #pragma unroll
  for (int f = 0; f < 16; ++f) v[f] = sm[grp][f];
  float o[4];
  #pragma unroll
  for (int j = 0; j < 4; ++j) o[j] = smb[ch * 4 + j];
  #pragma unroll
  for (int f = 0; f < 16; ++f)
    #pragma unroll
    for (int j = 0; j < 4; ++j)
      o[j] = fmaf(v[f], smw[f * HID + ch * 4 + j], o[j]);
  #pragma unroll
  for (int j = 0; j < 4; ++j)
    gout[((size_t)t * HID + ch * 4 + j) * N_NODES + dst] = fmaxf(o[j], 0.0f);
}

// ---- fused 2-layer GRU. block = 64 nodes (lane=node), 8 waves x 8 gate-triples ----
__global__ __launch_bounds__(512) void k_gru(const float* __restrict__ x,
                                             const float* __restrict__ wb,
                                             float* __restrict__ out){
  __shared__ float h0[HID][65];   // [hidden k][node n], pad 65 -> conflict-free
  __shared__ float h1[HID][65];
  const int lane = threadIdx.x & 63;
  const int j0 = (threadIdx.x >> 6) * 8;       // wave-uniform gate-triple base
  const int gn = blockIdx.x * 64 + lane;
  const bool valid = gn < N_NODES;
  for (int i = threadIdx.x; i < HID * 65; i += 512){
    (&h0[0][0])[i] = 0.0f; (&h1[0][0])[i] = 0.0f;
  }
  __syncthreads();
  const float* wih[2] = {wb,         wb + 24576};
  const float* whh[2] = {wb + 12288, wb + 36864};
  const float* bih[2] = {wb + 49152, wb + 49536};
  const float* bhh[2] = {wb + 49344, wb + 49728};
  for (int t = 0; t < SEQ_T; ++t){
    #pragma unroll
    for (int layer = 0; layer < 2; ++layer){
      float ax[3][8], ah[3][8];
      #pragma unroll
      for (int g = 0; g < 3; ++g)
        #pragma unroll
        for (int jj = 0; jj < 8; ++jj){
          ax[g][jj] = bih[layer][g * 64 + j0 + jj];
          ah[g][jj] = bhh[layer][g * 64 + j0 + jj];
        }
      const float* xt = x + (size_t)t * HID * N_NODES + gn;
      float (*hin)[65] = (layer == 0) ? h0 : h1;
      #pragma unroll 2
      for (int k = 0; k < HID; ++k){
        float xk = (layer == 0) ? (valid ? xt[(size_t)k * N_NODES] : 0.0f) : h0[k][lane];
        float hk = hin[k][lane];
        const float* wi = wih[layer] + k * 192 + j0;   // wave-uniform -> s_load
        const float* wh = whh[layer] + k * 192 + j0;
        #pragma unroll
        for (int g = 0; g < 3; ++g)
          #pragma unroll
          for (int jj = 0; jj < 8; ++jj){
            ax[g][jj] = fmaf(wi[g * 64 + jj], xk, ax[g][jj]);
            ah[g][jj] = fmaf(wh[g * 64 + jj], hk, ah[g][jj]);
          }
      }
      float hnew[8];
      #pragma unroll
      for (int jj = 0; jj < 8; ++jj){
        float hprev = hin[j0 + jj][lane];
        float r  = sigmf(ax[0][jj] + ah[0][jj]);
        float z  = sigmf(ax[1][jj] + ah[1][jj]);
        float ng = tanh_fast(ax[2][jj] + r * ah[2][jj]);
        hnew[jj] = (1.0f - z) * ng + z * hprev;
      }
      __syncthreads();
      #pragma unroll
      for (int jj = 0; jj < 8; ++jj) hin[j0 + jj][lane] = hnew[jj];
      if (layer == 1 && valid){
        #pragma unroll
        for (int jj = 0; jj < 8; ++jj)
          out[((size_t)t * HID + j0 + jj) * N_NODES + gn] = hnew[jj];
      }
      __syncthreads();
    }
  }
}

// ---- attention + fc + residual ----
__global__ void k_attn(const float* __restrict__ gru, const float* __restrict__ x,
                       const float* __restrict__ wb, float* __restrict__ out){
  int n = blockIdx.x * 64 + threadIdx.x;
  if (n >= N_NODES) return;
  const float* aw = wb + 51008;
  float ab = wb[51072];
  const float* fw = wb + 51073;
  float fb = wb[51137];
  float sc[SEQ_T], dc[SEQ_T];
  #pragma unroll
  for (int t = 0; t < SEQ_T; ++t){
    float s = ab, d = 0.0f;
    #pragma unroll
    for (int k = 0; k < HID; ++k){
      float v = gru[((size_t)t * HID + k) * N_NODES + n];
      s = fmaf(v, aw[k], s);
      d = fmaf(v, fw[k], d);
    }
    sc[t] = s; dc[t] = d;
  }
  float m = sc[0];
  #pragma unroll
  for (int t = 1; t < SEQ_T; ++t) m = fmaxf(m, sc[t]);
  float den = 0.0f, num = 0.0f;
  #pragma unroll
  for (int t = 0; t < SEQ_T; ++t){
    float p = __expf(sc[t] - m);
    den += p;
    num = fmaf(p, dc[t], num);
  }
  float y = fb + num / den;
  float last = x[((size_t)(SEQ_T - 1) * N_NODES + n) * IN_CH];   // x[11][n][0]
  out[n] = last + y;
}

extern "C" void kernel_launch(void* const* d_in, const int* in_sizes, int n_in,
                              void* d_out, int out_size, void* d_ws, size_t ws_size,
                              hipStream_t stream){
  const float* x = (const float*)d_in[0];   // fp32, (T,N,16)
  const int* ei  = (const int*)d_in[1];     // (2,E)
  char* ws = (char*)d_ws;
  float* wb      = (float*)(ws);                  // 51138 floats
  int*   cnt     = (int*)  (ws + 204800);         // 10000 ints (also the fill cursor)
  int*   row     = (int*)  (ws + 244800);         // 10001 ints
  float* dis     = (float*)(ws + 284804);         // 10000 floats
  int*   csr_src = (int*)  (ws + 324864);         // 160000 ints
  float* csr_w   = (float*)(ws + 964864);         // 160000 floats
  float* gout    = (float*)(ws + 1604864);        // (T,64,N) fp32 = 30,720,000 B
  float* ghid    = (float*)(ws + 32324864);       // (T,64,N) fp32 = 30,720,000 B

  k_prep<<<dim3(48, 15), 256, 0, stream>>>(
      (const float*)d_in[2],  (const float*)d_in[3],
      (const float*)d_in[4],  (const float*)d_in[5],
      (const float*)d_in[6],  (const float*)d_in[7],
      (const float*)d_in[8],  (const float*)d_in[9],
      (const float*)d_in[10], (const float*)d_in[11],
      (const float*)d_in[12], (const float*)d_in[13],
      (const float*)d_in[14], (const float*)d_in[15],
      wb, cnt);
  k_count<<<(N_EDGES + 255) / 256, 256, 0, stream>>>(ei, cnt);
  k_scan<<<1, 1024, 0, stream>>>(cnt, row, dis);
  k_fill<<<(N_EDGES + 255) / 256, 256, 0, stream>>>(ei, cnt, dis, csr_src, csr_w);
  k_gather_gcn<<<7500, 256, 0, stream>>>(x, row, csr_src, csr_w, dis, wb, gout);
  k_gru<<<(N_NODES + 63) / 64, 512, 0, stream>>>(gout, wb, ghid);
  k_attn<<<(N_NODES + 63) / 64, 64, 0, stream>>>(ghid, x, wb, (float*)d_out);
}

// Round 4
// 425.842 us; speedup vs baseline: 7.1900x; 3.4439x over previous
//
#include <hip/hip_runtime.h>
#include <hip/hip_bf16.h>

#define N_NODES 10000
#define SEQ_T 12
#define IN_CH 16
#define HID 64
#define N_EDGES 160000

typedef __attribute__((ext_vector_type(8))) short short8;
typedef __attribute__((ext_vector_type(4))) float floatx4;

// ---- helpers ----
__device__ __forceinline__ float sigmf(float x){ return 1.0f / (1.0f + __expf(-x)); }
__device__ __forceinline__ float tanh_fast(float x){ return 1.0f - 2.0f / (1.0f + __expf(2.0f * x)); }
__device__ __forceinline__ float bf2f(unsigned short u){
  union { unsigned int i; float f; } c; c.i = ((unsigned int)u) << 16; return c.f;
}
__device__ __forceinline__ unsigned short f2bf(float f){
  union { float f; unsigned int u; } c; c.f = f;
  unsigned int u = c.u;
  return (unsigned short)((u + 0x7FFFu + ((u >> 16) & 1u)) >> 16);   // RNE
}

// wb (fp32 param block) float offsets:
//   49152 b_ih0 192 | 49344 b_hh0 192 | 49536 b_ih1 192 | 49728 b_hh1 192
//   49920 gcn_w 1024 | 50944 gcn_b 64
//   51008 attn_w 64 | 51072 attn_b 1 | 51073 fc_w 64 | 51137 fc_b 1
// wF (bf16): 4 matrices (l0ih,l0hh,l1ih,l1hh) x [kt(2)][jt(12)][lane(64)][e(8)]
//   B-frag element = W[j = (lane&15)+16*jt][k = (lane>>4)*8 + e + 32*kt]

// ---- param prep: biases/gcn/attn fp32 copy + GRU weight frag-swizzle to bf16 + cnt init ----
__global__ void k_prep(const float* __restrict__ gcn_w,
                       const float* __restrict__ gcn_b,
                       const float* __restrict__ wih0,
                       const float* __restrict__ whh0,
                       const float* __restrict__ bih0,
                       const float* __restrict__ bhh0,
                       const float* __restrict__ wih1,
                       const float* __restrict__ whh1,
                       const float* __restrict__ bih1,
                       const float* __restrict__ bhh1,
                       const float* __restrict__ attn_w,
                       const float* __restrict__ attn_b,
                       const float* __restrict__ fc_w,
                       const float* __restrict__ fc_b,
                       float* __restrict__ wb, unsigned short* __restrict__ wF,
                       int* __restrict__ cnt){
  int p = blockIdx.y;
  int i = blockIdx.x * 256 + threadIdx.x;
  if (p == 14){ if (i < N_NODES) cnt[i] = 0; return; }
  const float* srcs[14] = {wih0, whh0, wih1, whh1, bih0, bhh0, bih1, bhh1,
                           gcn_w, gcn_b, attn_w, attn_b, fc_w, fc_b};
  const int sizes[14] = {12288,12288,12288,12288,192,192,192,192,1024,64,64,1,64,1};
  const int dsts[14]  = {0,0,0,0,49152,49344,49536,49728,49920,50944,51008,51072,51073,51137};
  if (i >= sizes[p]) return;
  if (p < 4){
    // frag swizzle: i = ((kt*12+jt)*64 + l)*8 + e
    int e = i & 7, l = (i >> 3) & 63, jk = i >> 9;
    int kt = jk / 12, jt = jk - kt * 12;
    int j = (l & 15) + 16 * jt;
    int k = ((l >> 4) * 8) + e + 32 * kt;
    wF[p * 12288 + i] = f2bf(srcs[p][j * 64 + k]);
  } else {
    wb[dsts[p] + i] = srcs[p][i];
  }
}

// ---- in-degree count over dst ----
__global__ void k_count(const int* __restrict__ ei, int* __restrict__ cnt){
  int e = blockIdx.x * 256 + threadIdx.x;
  if (e < N_EDGES) atomicAdd(&cnt[ei[N_EDGES + e]], 1);
}

// ---- exclusive scan -> row offsets; dis = rsqrt(deg); cursor=row (aliases cnt) ----
__global__ __launch_bounds__(1024) void k_scan(int* __restrict__ cnt_cursor,
                                               int* __restrict__ row,
                                               float* __restrict__ dis){
  __shared__ int sums[1024];
  const int CH = 10;
  int tid = threadIdx.x;
  int base = tid * CH;
  int local[CH]; int s = 0;
  #pragma unroll
  for (int i = 0; i < CH; ++i){
    int idx = base + i;
    int v = (idx < N_NODES) ? cnt_cursor[idx] : 0;
    local[i] = s;
    s += v;
    if (idx < N_NODES) dis[idx] = rsqrtf((float)v + 1.0f);
  }
  sums[tid] = s;
  __syncthreads();
  for (int off = 1; off < 1024; off <<= 1){
    int v = (tid >= off) ? sums[tid - off] : 0;
    __syncthreads();
    sums[tid] += v;
    __syncthreads();
  }
  int excl = sums[tid] - s;
  #pragma unroll
  for (int i = 0; i < CH; ++i){
    int idx = base + i;
    if (idx < N_NODES){
      int r = excl + local[i];
      row[idx] = r;
      cnt_cursor[idx] = r;
    }
  }
  if (tid == 1023) row[N_NODES] = sums[1023];
}

// ---- CSR fill ----
__global__ void k_fill(const int* __restrict__ ei, int* __restrict__ cursor,
                       const float* __restrict__ dis,
                       int* __restrict__ csr_src, float* __restrict__ csr_w){
  int e = blockIdx.x * 256 + threadIdx.x;
  if (e >= N_EDGES) return;
  int s = ei[e], d = ei[N_EDGES + e];
  int pos = atomicAdd(&cursor[d], 1);
  csr_src[pos] = s;
  csr_w[pos] = dis[s] * dis[d];
}

// ---- fused gather + GCN matmul + bias + relu -> goutF (bf16 A-frag order) ----
// goutF layout: [t][mt_g(625)][kt(2)][lane(64)][e(8)] bf16,
//   element = act[node = mt_g*16 + (lane&15)][k = kt*32 + (lane>>4)*8 + e]
__global__ __launch_bounds__(256) void k_gather_gcn(
    const float* __restrict__ x, const int* __restrict__ row,
    const int* __restrict__ csr_src, const float* __restrict__ csr_w,
    const float* __restrict__ dis, const float* __restrict__ wb,
    unsigned short* __restrict__ goutF){
  __shared__ float sm[16][16];
  __shared__ float smw[IN_CH * HID];
  __shared__ float smb[HID];
  int tid = threadIdx.x;
  for (int i = tid; i < IN_CH * HID; i += 256) smw[i] = wb[49920 + i];
  if (tid < HID) smb[tid] = wb[50944 + tid];
  int grp = tid >> 4, ch = tid & 15;
  int gid = blockIdx.x * 16 + grp;         // 7500*16 == 120000 exact
  int t = gid / N_NODES, dst = gid - t * N_NODES;
  float dd = dis[dst];
  float acc = dd * dd * x[((size_t)t * N_NODES + dst) * IN_CH + ch];   // self loop
  int r0 = row[dst], r1 = row[dst + 1];
  for (int e = r0; e < r1; ++e){
    int s = csr_src[e];
    float w = csr_w[e];
    acc = fmaf(w, x[((size_t)t * N_NODES + s) * IN_CH + ch], acc);
  }
  sm[grp][ch] = acc;
  __syncthreads();
  float v[16];
  #pragma unroll
  for (int f = 0; f < 16; ++f) v[f] = sm[grp][f];
  ushort4 ov;
  unsigned short o[4];
  #pragma unroll
  for (int j = 0; j < 4; ++j){
    float a = smb[ch * 4 + j];
    #pragma unroll
    for (int f = 0; f < 16; ++f) a = fmaf(v[f], smw[f * HID + ch * 4 + j], a);
    o[j] = f2bf(fmaxf(a, 0.0f));
  }
  ov.x = o[0]; ov.y = o[1]; ov.z = o[2]; ov.w = o[3];
  // h-channels ch*4+q: kt=ch>>3, lane=(dst&15)+16*((ch>>1)&3), e=(ch&1)*4+q
  size_t addr = ((((size_t)t * 625 + (dst >> 4)) * 2 + (ch >> 3)) * 64
                 + (dst & 15) + 16 * ((ch >> 1) & 3)) * 8 + (ch & 1) * 4;
  *(ushort4*)(goutF + addr) = ov;
}

// ---- fused 2-layer GRU on MFMA. block = 64 nodes (4 m-tiles), 4 waves. ----
// wave w owns j-tiles {w, w+4, w+8} => lane's 3 acc slots are the r/z/n gates
// of the SAME hidden unit hb = w*16+(lane&15), nodes mt*16+(lane>>4)*4+r.
__global__ __launch_bounds__(256, 1) void k_gru(
    const unsigned short* __restrict__ goutF, const unsigned short* __restrict__ wF,
    const float* __restrict__ wb, unsigned short* __restrict__ h0F,
    unsigned short* __restrict__ ghid){
  __shared__ unsigned short hF[4 * 2 * 64 * 8];   // h in A-frag order, bf16
  const int tid = threadIdx.x;
  const int w = tid >> 6;
  const int l = tid & 63;
  const int c = l & 15;
  const int q = l >> 4;
  const int hb = w * 16 + c;            // hidden index owned by this lane
  const int kt_h = hb >> 5;
  const int e_h = hb & 7;
  const int lf_h = 16 * ((hb >> 3) & 3);
  const int blk = blockIdx.x;
  int mtg[4];
  #pragma unroll
  for (int mt = 0; mt < 4; ++mt) mtg[mt] = blk * 4 + mt;

  for (int i = tid; i < 4 * 2 * 64 * 8; i += 256) hF[i] = 0;

  float hprev[4][4];

  for (int layer = 0; layer < 2; ++layer){
    if (layer == 1){
      __syncthreads();
      for (int i = tid; i < 4 * 2 * 64 * 8; i += 256) hF[i] = 0;
    }
    #pragma unroll
    for (int mt = 0; mt < 4; ++mt)
      #pragma unroll
      for (int r = 0; r < 4; ++r) hprev[mt][r] = 0.0f;

    const float* bi = wb + 49152 + layer * 384;
    const float* bh = bi + 192;
    float bir = bi[hb], biz = bi[64 + hb], bin = bi[128 + hb];
    float bhr = bh[hb], bhz = bh[64 + hb], bhn = bh[128 + hb];

    // B-frags held in registers for the whole layer
    short8 bw[2][3][2];   // [g: ih/hh][slot: jt=w+4*s][kt]
    #pragma unroll
    for (int g = 0; g < 2; ++g)
      #pragma unroll
      for (int s = 0; s < 3; ++s)
        #pragma unroll
        for (int kt = 0; kt < 2; ++kt){
          int jt = w + 4 * s;
          size_t idx = ((((size_t)(layer * 2 + g) * 2 + kt) * 12 + jt) * 64 + l) * 8;
          bw[g][s][kt] = *(const short8*)(wF + idx);
        }

    const unsigned short* xsrc = (layer == 0) ? goutF : h0F;
    short8 xa[8], xb[8];
    #pragma unroll
    for (int mt = 0; mt < 4; ++mt){
      int mc = mtg[mt] < 625 ? mtg[mt] : 624;
      #pragma unroll
      for (int kt = 0; kt < 2; ++kt)
        xa[mt * 2 + kt] = *(const short8*)(xsrc + (((size_t)0 * 625 + mc) * 2 + kt) * 512 + l * 8);
    }
    __syncthreads();

    for (int t = 0; t < SEQ_T; ++t){
      int tn = (t + 1 < SEQ_T) ? t + 1 : t;
      #pragma unroll
      for (int mt = 0; mt < 4; ++mt){
        int mc = mtg[mt] < 625 ? mtg[mt] : 624;
        #pragma unroll
        for (int kt = 0; kt < 2; ++kt)
          xb[mt * 2 + kt] = *(const short8*)(xsrc + (((size_t)tn * 625 + mc) * 2 + kt) * 512 + l * 8);
      }
      short8 ha[8];
      #pragma unroll
      for (int mt = 0; mt < 4; ++mt)
        #pragma unroll
        for (int kt = 0; kt < 2; ++kt)
          ha[mt * 2 + kt] = *(const short8*)&hF[((mt * 2 + kt) * 64 + l) * 8];

      floatx4 acc[2][3][4];
      #pragma unroll
      for (int g = 0; g < 2; ++g)
        #pragma unroll
        for (int s = 0; s < 3; ++s)
          #pragma unroll
          for (int mt = 0; mt < 4; ++mt)
            acc[g][s][mt] = (floatx4){0.f, 0.f, 0.f, 0.f};
      #pragma unroll
      for (int s = 0; s < 3; ++s)
        #pragma unroll
        for (int mt = 0; mt < 4; ++mt)
          #pragma unroll
          for (int kt = 0; kt < 2; ++kt){
            acc[0][s][mt] = __builtin_amdgcn_mfma_f32_16x16x32_bf16(
                xa[mt * 2 + kt], bw[0][s][kt], acc[0][s][mt], 0, 0, 0);
            acc[1][s][mt] = __builtin_amdgcn_mfma_f32_16x16x32_bf16(
                ha[mt * 2 + kt], bw[1][s][kt], acc[1][s][mt], 0, 0, 0);
          }
      __syncthreads();   // all waves done reading old hF

      #pragma unroll
      for (int mt = 0; mt < 4; ++mt){
        bool vmt = mtg[mt] < 625;
        unsigned short hnb[4];
        #pragma unroll
        for (int r = 0; r < 4; ++r){
          float rr = sigmf(acc[0][0][mt][r] + acc[1][0][mt][r] + bir + bhr);
          float zz = sigmf(acc[0][1][mt][r] + acc[1][1][mt][r] + biz + bhz);
          float nn = tanh_fast(acc[0][2][mt][r] + bin + rr * (acc[1][2][mt][r] + bhn));
          float hn = (1.0f - zz) * nn + zz * hprev[mt][r];
          hprev[mt][r] = hn;
          hnb[r] = f2bf(hn);
          hF[((mt * 2 + kt_h) * 64 + (q * 4 + r) + lf_h) * 8 + e_h] = hnb[r];
        }
        if (layer == 0){
          if (vmt){
            #pragma unroll
            for (int r = 0; r < 4; ++r)
              h0F[(((size_t)t * 625 + mtg[mt]) * 2 + kt_h) * 512
                  + ((q * 4 + r) + lf_h) * 8 + e_h] = hnb[r];
          }
        } else {
          if (vmt){
            ushort4 ov; ov.x = hnb[0]; ov.y = hnb[1]; ov.z = hnb[2]; ov.w = hnb[3];
            *(ushort4*)(ghid + ((size_t)t * 64 + hb) * 10000 + mtg[mt] * 16 + q * 4) = ov;
          }
        }
      }
      __syncthreads();   // new hF visible before next step's reads

      #pragma unroll
      for (int i = 0; i < 8; ++i) xa[i] = xb[i];
    }
  }
}

// ---- attention + fc + residual (reads bf16 ghid) ----
__global__ void k_attn(const unsigned short* __restrict__ gru, const float* __restrict__ x,
                       const float* __restrict__ wb, float* __restrict__ out){
  int n = blockIdx.x * 64 + threadIdx.x;
  if (n >= N_NODES) return;
  const float* aw = wb + 51008;
  float ab = wb[51072];
  const float* fw = wb + 51073;
  float fb = wb[51137];
  float sc[SEQ_T], dc[SEQ_T];
  #pragma unroll
  for (int t = 0; t < SEQ_T; ++t){
    float s = ab, d = 0.0f;
    #pragma unroll
    for (int k = 0; k < HID; ++k){
      float v = bf2f(gru[((size_t)t * HID + k) * N_NODES + n]);
      s = fmaf(v, aw[k], s);
      d = fmaf(v, fw[k], d);
    }
    sc[t] = s; dc[t] = d;
  }
  float m = sc[0];
  #pragma unroll
  for (int t = 1; t < SEQ_T; ++t) m = fmaxf(m, sc[t]);
  float den = 0.0f, num = 0.0f;
  #pragma unroll
  for (int t = 0; t < SEQ_T; ++t){
    float p = __expf(sc[t] - m);
    den += p;
    num = fmaf(p, dc[t], num);
  }
  float y = fb + num / den;
  float last = x[((size_t)(SEQ_T - 1) * N_NODES + n) * IN_CH];   // x[11][n][0]
  out[n] = last + y;
}

extern "C" void kernel_launch(void* const* d_in, const int* in_sizes, int n_in,
                              void* d_out, int out_size, void* d_ws, size_t ws_size,
                              hipStream_t stream){
  const float* x = (const float*)d_in[0];   // fp32, (T,N,16)
  const int* ei  = (const int*)d_in[1];     // (2,E)
  char* ws = (char*)d_ws;
  float*          wb      = (float*)(ws);                  // 51138 floats
  unsigned short* wF      = (unsigned short*)(ws + 262144);// 49152 bf16 = 98304 B
  int*            cnt     = (int*)(ws + 393216);           // 10000 (also fill cursor)
  int*            row     = (int*)(ws + 433216);           // 10001
  float*          dis     = (float*)(ws + 473280);         // 10000
  int*            csr_src = (int*)(ws + 513280);           // 160000
  float*          csr_w   = (float*)(ws + 1153280);        // 160000
  unsigned short* goutF   = (unsigned short*)(ws + 1793280);  // 12*625*1024 bf16 = 15.36 MB
  unsigned short* h0F     = (unsigned short*)(ws + 17153280); // 15.36 MB
  unsigned short* ghid    = (unsigned short*)(ws + 32513280); // 12*64*10000 bf16 = 15.36 MB

  k_prep<<<dim3(48, 15), 256, 0, stream>>>(
      (const float*)d_in[2],  (const float*)d_in[3],
      (const float*)d_in[4],  (const float*)d_in[5],
      (const float*)d_in[6],  (const float*)d_in[7],
      (const float*)d_in[8],  (const float*)d_in[9],
      (const float*)d_in[10], (const float*)d_in[11],
      (const float*)d_in[12], (const float*)d_in[13],
      (const float*)d_in[14], (const float*)d_in[15],
      wb, wF, cnt);
  k_count<<<(N_EDGES + 255) / 256, 256, 0, stream>>>(ei, cnt);
  k_scan<<<1, 1024, 0, stream>>>(cnt, row, dis);
  k_fill<<<(N_EDGES + 255) / 256, 256, 0, stream>>>(ei, cnt, dis, csr_src, csr_w);
  k_gather_gcn<<<7500, 256, 0, stream>>>(x, row, csr_src, csr_w, dis, wb, goutF);
  k_gru<<<(N_NODES + 63) / 64, 256, 0, stream>>>(goutF, wF, wb, h0F, ghid);
  k_attn<<<(N_NODES + 63) / 64, 64, 0, stream>>>(ghid, x, wb, (float*)d_out);
}

// Round 5
// 251.040 us; speedup vs baseline: 12.1965x; 1.6963x over previous
//
#include <hip/hip_runtime.h>
#include <hip/hip_bf16.h>

#define N_NODES 10000
#define SEQ_T 12
#define IN_CH 16
#define HID 64
#define N_EDGES 160000

typedef __attribute__((ext_vector_type(8))) short short8;
typedef __attribute__((ext_vector_type(4))) float floatx4;

// ---- helpers ----
__device__ __forceinline__ float sigmf(float x){ return 1.0f / (1.0f + __expf(-x)); }
__device__ __forceinline__ float tanh_fast(float x){ return 1.0f - 2.0f / (1.0f + __expf(2.0f * x)); }
__device__ __forceinline__ float bf2f(unsigned short u){
  union { unsigned int i; float f; } c; c.i = ((unsigned int)u) << 16; return c.f;
}
__device__ __forceinline__ unsigned short f2bf(float f){
  union { float f; unsigned int u; } c; c.f = f;
  unsigned int u = c.u;
  return (unsigned short)((u + 0x7FFFu + ((u >> 16) & 1u)) >> 16);   // RNE
}

// wb (fp32 param block) float offsets:
//   49152 b_ih0 192 | 49344 b_hh0 192 | 49536 b_ih1 192 | 49728 b_hh1 192
//   49920 gcn_w 1024 | 50944 gcn_b 64
//   51008 attn_w 64 | 51072 attn_b 1 | 51073 fc_w 64 | 51137 fc_b 1
// wF (bf16): 4 matrices (l0ih,l0hh,l1ih,l1hh) x [kt(2)][jt(12)][lane(64)][e(8)]
//   B-frag element = W[j = (lane&15)+16*jt][k = (lane>>4)*8 + e + 32*kt]

// ---- param prep: biases/gcn/attn fp32 copy + GRU weight frag-swizzle to bf16 + cnt init ----
__global__ void k_prep(const float* __restrict__ gcn_w,
                       const float* __restrict__ gcn_b,
                       const float* __restrict__ wih0,
                       const float* __restrict__ whh0,
                       const float* __restrict__ bih0,
                       const float* __restrict__ bhh0,
                       const float* __restrict__ wih1,
                       const float* __restrict__ whh1,
                       const float* __restrict__ bih1,
                       const float* __restrict__ bhh1,
                       const float* __restrict__ attn_w,
                       const float* __restrict__ attn_b,
                       const float* __restrict__ fc_w,
                       const float* __restrict__ fc_b,
                       float* __restrict__ wb, unsigned short* __restrict__ wF,
                       int* __restrict__ cnt){
  int p = blockIdx.y;
  int i = blockIdx.x * 256 + threadIdx.x;
  if (p == 14){ if (i < N_NODES) cnt[i] = 0; return; }
  const float* srcs[14] = {wih0, whh0, wih1, whh1, bih0, bhh0, bih1, bhh1,
                           gcn_w, gcn_b, attn_w, attn_b, fc_w, fc_b};
  const int sizes[14] = {12288,12288,12288,12288,192,192,192,192,1024,64,64,1,64,1};
  const int dsts[14]  = {0,0,0,0,49152,49344,49536,49728,49920,50944,51008,51072,51073,51137};
  if (i >= sizes[p]) return;
  if (p < 4){
    // frag swizzle: i = ((kt*12+jt)*64 + l)*8 + e
    int e = i & 7, l = (i >> 3) & 63, jk = i >> 9;
    int kt = jk / 12, jt = jk - kt * 12;
    int j = (l & 15) + 16 * jt;
    int k = ((l >> 4) * 8) + e + 32 * kt;
    wF[p * 12288 + i] = f2bf(srcs[p][j * 64 + k]);
  } else {
    wb[dsts[p] + i] = srcs[p][i];
  }
}

// ---- in-degree count over dst ----
__global__ void k_count(const int* __restrict__ ei, int* __restrict__ cnt){
  int e = blockIdx.x * 256 + threadIdx.x;
  if (e < N_EDGES) atomicAdd(&cnt[ei[N_EDGES + e]], 1);
}

// ---- exclusive scan -> row offsets; dis = rsqrt(deg); cursor=row (aliases cnt) ----
__global__ __launch_bounds__(1024) void k_scan(int* __restrict__ cnt_cursor,
                                               int* __restrict__ row,
                                               float* __restrict__ dis){
  __shared__ int sums[1024];
  const int CH = 10;
  int tid = threadIdx.x;
  int base = tid * CH;
  int local[CH]; int s = 0;
  #pragma unroll
  for (int i = 0; i < CH; ++i){
    int idx = base + i;
    int v = (idx < N_NODES) ? cnt_cursor[idx] : 0;
    local[i] = s;
    s += v;
    if (idx < N_NODES) dis[idx] = rsqrtf((float)v + 1.0f);
  }
  sums[tid] = s;
  __syncthreads();
  for (int off = 1; off < 1024; off <<= 1){
    int v = (tid >= off) ? sums[tid - off] : 0;
    __syncthreads();
    sums[tid] += v;
    __syncthreads();
  }
  int excl = sums[tid] - s;
  #pragma unroll
  for (int i = 0; i < CH; ++i){
    int idx = base + i;
    if (idx < N_NODES){
      int r = excl + local[i];
      row[idx] = r;
      cnt_cursor[idx] = r;
    }
  }
  if (tid == 1023) row[N_NODES] = sums[1023];
}

// ---- CSR fill ----
__global__ void k_fill(const int* __restrict__ ei, int* __restrict__ cursor,
                       const float* __restrict__ dis,
                       int* __restrict__ csr_src, float* __restrict__ csr_w){
  int e = blockIdx.x * 256 + threadIdx.x;
  if (e >= N_EDGES) return;
  int s = ei[e], d = ei[N_EDGES + e];
  int pos = atomicAdd(&cursor[d], 1);
  csr_src[pos] = s;
  csr_w[pos] = dis[s] * dis[d];
}

// ---- fused gather + GCN matmul + bias + relu -> goutF (bf16 A-frag order) ----
// goutF layout: [t][mt_g(625)][kt(2)][lane(64)][e(8)] bf16,
//   element = act[node = mt_g*16 + (lane&15)][k = kt*32 + (lane>>4)*8 + e]
__global__ __launch_bounds__(256) void k_gather_gcn(
    const float* __restrict__ x, const int* __restrict__ row,
    const int* __restrict__ csr_src, const float* __restrict__ csr_w,
    const float* __restrict__ dis, const float* __restrict__ wb,
    unsigned short* __restrict__ goutF){
  __shared__ float sm[16][16];
  __shared__ float smw[IN_CH * HID];
  __shared__ float smb[HID];
  int tid = threadIdx.x;
  for (int i = tid; i < IN_CH * HID; i += 256) smw[i] = wb[49920 + i];
  if (tid < HID) smb[tid] = wb[50944 + tid];
  int grp = tid >> 4, ch = tid & 15;
  int gid = blockIdx.x * 16 + grp;         // 7500*16 == 120000 exact
  int t = gid / N_NODES, dst = gid - t * N_NODES;
  float dd = dis[dst];
  float acc = dd * dd * x[((size_t)t * N_NODES + dst) * IN_CH + ch];   // self loop
  int r0 = row[dst], r1 = row[dst + 1];
  for (int e = r0; e < r1; ++e){
    int s = csr_src[e];
    float w = csr_w[e];
    acc = fmaf(w, x[((size_t)t * N_NODES + s) * IN_CH + ch], acc);
  }
  sm[grp][ch] = acc;
  __syncthreads();
  float v[16];
  #pragma unroll
  for (int f = 0; f < 16; ++f) v[f] = sm[grp][f];
  ushort4 ov;
  unsigned short o[4];
  #pragma unroll
  for (int j = 0; j < 4; ++j){
    float a = smb[ch * 4 + j];
    #pragma unroll
    for (int f = 0; f < 16; ++f) a = fmaf(v[f], smw[f * HID + ch * 4 + j], a);
    o[j] = f2bf(fmaxf(a, 0.0f));
  }
  ov.x = o[0]; ov.y = o[1]; ov.z = o[2]; ov.w = o[3];
  // h-channels ch*4+q: kt=ch>>3, lane=(dst&15)+16*((ch>>1)&3), e=(ch&1)*4+q
  size_t addr = ((((size_t)t * 625 + (dst >> 4)) * 2 + (ch >> 3)) * 64
                 + (dst & 15) + 16 * ((ch >> 1) & 3)) * 8 + (ch & 1) * 4;
  *(ushort4*)(goutF + addr) = ov;
}

// ---- fused 2-layer GRU on MFMA + attention/FC/residual epilogue. ----
// block = 64 nodes (4 m-tiles), 4 waves; wave w owns j-tiles {w, w+4, w+8}.
// Attention: sc[t]=attn_w.h_t, dc[t]=fc_w.h_t via one extra B-frag (cols 0/1),
// computed by wave 0 from the already-loaded ha frags (h_{t-1}); softmax at end.
__global__ __launch_bounds__(256, 1) void k_gru(
    const unsigned short* __restrict__ goutF, const unsigned short* __restrict__ wF,
    const float* __restrict__ wb, unsigned short* __restrict__ h0F,
    const float* __restrict__ x, float* __restrict__ out){
  __shared__ unsigned short hF[4 * 2 * 64 * 8];   // h in A-frag order, bf16
  __shared__ float scdc[SEQ_T][2][64];            // [t][sc/dc][node]
  const int tid = threadIdx.x;
  const int w = tid >> 6;
  const int l = tid & 63;
  const int c = l & 15;
  const int q = l >> 4;
  const int hb = w * 16 + c;            // hidden index owned by this lane
  const int kt_h = hb >> 5;
  const int e_h = hb & 7;
  const int lf_h = 16 * ((hb >> 3) & 3);
  const int blk = blockIdx.x;
  int mtg[4];
  #pragma unroll
  for (int mt = 0; mt < 4; ++mt) mtg[mt] = blk * 4 + mt;

  for (int i = tid; i < 4 * 2 * 64 * 8; i += 256) hF[i] = 0;

  // attn/fc B-frag: col j=0 -> attn_w, j=1 -> fc_w, else 0 (bf16)
  short8 bwA[2];
  #pragma unroll
  for (int kt = 0; kt < 2; ++kt){
    short8 v;
    #pragma unroll
    for (int e = 0; e < 8; ++e){
      int k = q * 8 + e + 32 * kt;
      float f = (c == 0) ? wb[51008 + k] : (c == 1) ? wb[51073 + k] : 0.0f;
      v[e] = (short)f2bf(f);
    }
    bwA[kt] = v;
  }

  float hprev[4][4];

  #pragma unroll
  for (int layer = 0; layer < 2; ++layer){
    if (layer == 1){
      __syncthreads();
      for (int i = tid; i < 4 * 2 * 64 * 8; i += 256) hF[i] = 0;
    }
    #pragma unroll
    for (int mt = 0; mt < 4; ++mt)
      #pragma unroll
      for (int r = 0; r < 4; ++r) hprev[mt][r] = 0.0f;

    const float* bi = wb + 49152 + layer * 384;
    const float* bh = bi + 192;
    float bir = bi[hb], biz = bi[64 + hb], bin = bi[128 + hb];
    float bhr = bh[hb], bhz = bh[64 + hb], bhn = bh[128 + hb];

    // B-frags held in registers for the whole layer
    short8 bw[2][3][2];   // [g: ih/hh][slot: jt=w+4*s][kt]
    #pragma unroll
    for (int g = 0; g < 2; ++g)
      #pragma unroll
      for (int s = 0; s < 3; ++s)
        #pragma unroll
        for (int kt = 0; kt < 2; ++kt){
          int jt = w + 4 * s;
          size_t idx = ((((size_t)(layer * 2 + g) * 2 + kt) * 12 + jt) * 64 + l) * 8;
          bw[g][s][kt] = *(const short8*)(wF + idx);
        }

    const unsigned short* xsrc = (layer == 0) ? goutF : h0F;
    short8 xa[8], xb[8];
    #pragma unroll
    for (int mt = 0; mt < 4; ++mt){
      int mc = mtg[mt] < 625 ? mtg[mt] : 624;
      #pragma unroll
      for (int kt = 0; kt < 2; ++kt)
        xa[mt * 2 + kt] = *(const short8*)(xsrc + (((size_t)0 * 625 + mc) * 2 + kt) * 512 + l * 8);
    }
    __syncthreads();

    for (int t = 0; t < SEQ_T; ++t){
      int tn = (t + 1 < SEQ_T) ? t + 1 : t;
      #pragma unroll
      for (int mt = 0; mt < 4; ++mt){
        int mc = mtg[mt] < 625 ? mtg[mt] : 624;
        #pragma unroll
        for (int kt = 0; kt < 2; ++kt)
          xb[mt * 2 + kt] = *(const short8*)(xsrc + (((size_t)tn * 625 + mc) * 2 + kt) * 512 + l * 8);
      }
      short8 ha[8];
      #pragma unroll
      for (int mt = 0; mt < 4; ++mt)
        #pragma unroll
        for (int kt = 0; kt < 2; ++kt)
          ha[mt * 2 + kt] = *(const short8*)&hF[((mt * 2 + kt) * 64 + l) * 8];

      floatx4 acc[2][3][4];
      #pragma unroll
      for (int g = 0; g < 2; ++g)
        #pragma unroll
        for (int s = 0; s < 3; ++s)
          #pragma unroll
          for (int mt = 0; mt < 4; ++mt)
            acc[g][s][mt] = (floatx4){0.f, 0.f, 0.f, 0.f};
      #pragma unroll
      for (int s = 0; s < 3; ++s)
        #pragma unroll
        for (int mt = 0; mt < 4; ++mt)
          #pragma unroll
          for (int kt = 0; kt < 2; ++kt){
            acc[0][s][mt] = __builtin_amdgcn_mfma_f32_16x16x32_bf16(
                xa[mt * 2 + kt], bw[0][s][kt], acc[0][s][mt], 0, 0, 0);
            acc[1][s][mt] = __builtin_amdgcn_mfma_f32_16x16x32_bf16(
                ha[mt * 2 + kt], bw[1][s][kt], acc[1][s][mt], 0, 0, 0);
          }
      // attention dots of h_{t-1} (ha), wave 0 only; scdc[t-1]
      if (layer == 1 && w == 0 && t >= 1){
        floatx4 aA[4];
        #pragma unroll
        for (int mt = 0; mt < 4; ++mt){
          aA[mt] = (floatx4){0.f, 0.f, 0.f, 0.f};
          #pragma unroll
          for (int kt = 0; kt < 2; ++kt)
            aA[mt] = __builtin_amdgcn_mfma_f32_16x16x32_bf16(
                ha[mt * 2 + kt], bwA[kt], aA[mt], 0, 0, 0);
        }
        if (c < 2){
          #pragma unroll
          for (int mt = 0; mt < 4; ++mt)
            #pragma unroll
            for (int r = 0; r < 4; ++r)
              scdc[t - 1][c][mt * 16 + q * 4 + r] = aA[mt][r];
        }
      }
      __syncthreads();   // all waves done reading old hF

      #pragma unroll
      for (int mt = 0; mt < 4; ++mt){
        bool vmt = mtg[mt] < 625;
        unsigned short hnb[4];
        #pragma unroll
        for (int r = 0; r < 4; ++r){
          float rr = sigmf(acc[0][0][mt][r] + acc[1][0][mt][r] + bir + bhr);
          float zz = sigmf(acc[0][1][mt][r] + acc[1][1][mt][r] + biz + bhz);
          float nn = tanh_fast(acc[0][2][mt][r] + bin + rr * (acc[1][2][mt][r] + bhn));
          float hn = (1.0f - zz) * nn + zz * hprev[mt][r];
          hprev[mt][r] = hn;
          hnb[r] = f2bf(hn);
          hF[((mt * 2 + kt_h) * 64 + (q * 4 + r) + lf_h) * 8 + e_h] = hnb[r];
        }
        if (layer == 0 && vmt){
          #pragma unroll
          for (int r = 0; r < 4; ++r)
            h0F[(((size_t)t * 625 + mtg[mt]) * 2 + kt_h) * 512
                + ((q * 4 + r) + lf_h) * 8 + e_h] = hnb[r];
        }
      }
      __syncthreads();   // new hF visible before next step's reads

      #pragma unroll
      for (int i = 0; i < 8; ++i) xa[i] = xb[i];
    }
  }

  // final attention dots for h_11 (hF holds layer-1 h_11 now)
  if (w == 0){
    short8 hL[8];
    #pragma unroll
    for (int mt = 0; mt < 4; ++mt)
      #pragma unroll
      for (int kt = 0; kt < 2; ++kt)
        hL[mt * 2 + kt] = *(const short8*)&hF[((mt * 2 + kt) * 64 + l) * 8];
    floatx4 aA[4];
    #pragma unroll
    for (int mt = 0; mt < 4; ++mt){
      aA[mt] = (floatx4){0.f, 0.f, 0.f, 0.f};
      #pragma unroll
      for (int kt = 0; kt < 2; ++kt)
        aA[mt] = __builtin_amdgcn_mfma_f32_16x16x32_bf16(
            hL[mt * 2 + kt], bwA[kt], aA[mt], 0, 0, 0);
    }
    if (c < 2){
      #pragma unroll
      for (int mt = 0; mt < 4; ++mt)
        #pragma unroll
        for (int r = 0; r < 4; ++r)
          scdc[SEQ_T - 1][c][mt * 16 + q * 4 + r] = aA[mt][r];
    }
    // epilogue: softmax over t + fc bias + residual (wave 0, lane = local node)
    int gn = blk * 64 + l;
    if (gn < N_NODES){
      float sc[SEQ_T], dc[SEQ_T];
      #pragma unroll
      for (int t = 0; t < SEQ_T; ++t){ sc[t] = scdc[t][0][l]; dc[t] = scdc[t][1][l]; }
      float m = sc[0];
      #pragma unroll
      for (int t = 1; t < SEQ_T; ++t) m = fmaxf(m, sc[t]);
      float den = 0.0f, num = 0.0f;
      #pragma unroll
      for (int t = 0; t < SEQ_T; ++t){
        float p = __expf(sc[t] - m);
        den += p;
        num = fmaf(p, dc[t], num);
      }
      float y = wb[51137] + num / den;
      float last = x[((size_t)(SEQ_T - 1) * N_NODES + gn) * IN_CH];   // x[11][n][0]
      out[gn] = last + y;
    }
  }
}

extern "C" void kernel_launch(void* const* d_in, const int* in_sizes, int n_in,
                              void* d_out, int out_size, void* d_ws, size_t ws_size,
                              hipStream_t stream){
  const float* x = (const float*)d_in[0];   // fp32, (T,N,16)
  const int* ei  = (const int*)d_in[1];     // (2,E)
  char* ws = (char*)d_ws;
  float*          wb      = (float*)(ws);                  // 51138 floats
  unsigned short* wF      = (unsigned short*)(ws + 262144);// 49152 bf16 = 98304 B
  int*            cnt     = (int*)(ws + 393216);           // 10000 (also fill cursor)
  int*            row     = (int*)(ws + 433216);           // 10001
  float*          dis     = (float*)(ws + 473280);         // 10000
  int*            csr_src = (int*)(ws + 513280);           // 160000
  float*          csr_w   = (float*)(ws + 1153280);        // 160000
  unsigned short* goutF   = (unsigned short*)(ws + 1793280);  // 12*625*1024 bf16 = 15.36 MB
  unsigned short* h0F     = (unsigned short*)(ws + 17153280); // 15.36 MB

  k_prep<<<dim3(48, 15), 256, 0, stream>>>(
      (const float*)d_in[2],  (const float*)d_in[3],
      (const float*)d_in[4],  (const float*)d_in[5],
      (const float*)d_in[6],  (const float*)d_in[7],
      (const float*)d_in[8],  (const float*)d_in[9],
      (const float*)d_in[10], (const float*)d_in[11],
      (const float*)d_in[12], (const float*)d_in[13],
      (const float*)d_in[14], (const float*)d_in[15],
      wb, wF, cnt);
  k_count<<<(N_EDGES + 255) / 256, 256, 0, stream>>>(ei, cnt);
  k_scan<<<1, 1024, 0, stream>>>(cnt, row, dis);
  k_fill<<<(N_EDGES + 255) / 256, 256, 0, stream>>>(ei, cnt, dis, csr_src, csr_w);
  k_gather_gcn<<<7500, 256, 0, stream>>>(x, row, csr_src, csr_w, dis, wb, goutF);
  k_gru<<<(N_NODES + 63) / 64, 256, 0, stream>>>(goutF, wF, wb, h0F, x, (float*)d_out);
}